// Round 7
// baseline (326.895 us; speedup 1.0000x reference)
//
#include <hip/hip_runtime.h>
#include <cmath>

#define NN 50000
#define KK 15
#define DD 128
#define HH 64
#define NKE (NN * KK)
// ws layout (big path): [ xT : DD*NN ][ XA : NN*HH ][ XB : NN*HH ][ XC : NN*HH ]
#define TOFF ((size_t)DD * NN)
#define WS_NEED ((TOFF + 3 * (size_t)NN * HH) * 4)

// ---------------------------------------------------------------------------
// kT: transpose x (NN x DD) -> xT (DD x NN) via padded LDS tile.
// 64 rows x 128 cols per block; both global sides coalesced (256 B/wave).
// ---------------------------------------------------------------------------
__global__ __launch_bounds__(256) void kT(const float* __restrict__ x,
                                          float* __restrict__ xT) {
    __shared__ float s[64][DD + 1];
    int t = threadIdx.x;
    int r0 = blockIdx.x * 64;
#pragma unroll
    for (int i = 0; i < 8; ++i) {
        int idx = i * 256 + t;              // float4 index in 64x128 tile
        int rr = idx >> 5, cc = idx & 31;
        if (r0 + rr < NN) {
            float4 v = *(const float4*)(x + (size_t)(r0 + rr) * DD + cc * 4);
            s[rr][cc * 4 + 0] = v.x; s[rr][cc * 4 + 1] = v.y;
            s[rr][cc * 4 + 2] = v.z; s[rr][cc * 4 + 3] = v.w;
        }
    }
    __syncthreads();
    int lane = t & 63, wq = t >> 6;
    int n = r0 + lane;
    if (n >= NN) return;
#pragma unroll
    for (int i = 0; i < 32; ++i) {
        int k = i * 4 + wq;
        xT[(size_t)k * NN + n] = s[lane][k];   // coalesced 256 B
    }
}

// ---------------------------------------------------------------------------
// kP2: kE-shaped per-node GEMM, one segment per blockIdx.y.
//   seg0: XA = x @ ew1[0:128]; seg1: XB = x @ ew1[128:256]; seg2: XC = x @ dw1
// thread = node; acc[64] (AGPR); per k4: 4 COALESCED xT loads (lane=n) +
// 16 uniform float4 W-row loads (s_load, 32 KB sK$/L2-hot).  Same operand
// roles as kE (proven 60% VALUBusy shape) — no broadcast of streamed data.
// ---------------------------------------------------------------------------
__global__ __launch_bounds__(128, 4) void kP2(const float* __restrict__ xT,
                                              const float* __restrict__ ew1,
                                              const float* __restrict__ dw1,
                                              float* __restrict__ xabc) {
    int seg = blockIdx.y;
    const float* W = (seg == 0) ? ew1 : (seg == 1) ? (ew1 + DD * HH) : dw1;
    float* o = xabc + (size_t)seg * NN * HH;
    int n = blockIdx.x * 128 + threadIdx.x;
    if (n >= NN) return;

    float acc[HH];
#pragma unroll
    for (int j = 0; j < HH; ++j) acc[j] = 0.f;

#pragma unroll 1
    for (int k4 = 0; k4 < DD / 4; ++k4) {
        float x0 = xT[(size_t)(k4 * 4 + 0) * NN + n];   // coalesced dword
        float x1 = xT[(size_t)(k4 * 4 + 1) * NN + n];
        float x2 = xT[(size_t)(k4 * 4 + 2) * NN + n];
        float x3 = xT[(size_t)(k4 * 4 + 3) * NN + n];
        float xv[4] = {x0, x1, x2, x3};
#pragma unroll
        for (int m = 0; m < 4; ++m) {
            const float* wr = W + (k4 * 4 + m) * HH;     // uniform -> s_load
#pragma unroll
            for (int j4 = 0; j4 < 16; ++j4) {
                float4 w = *(const float4*)(wr + j4 * 4);
                acc[j4 * 4 + 0] = fmaf(xv[m], w.x, acc[j4 * 4 + 0]);
                acc[j4 * 4 + 1] = fmaf(xv[m], w.y, acc[j4 * 4 + 1]);
                acc[j4 * 4 + 2] = fmaf(xv[m], w.z, acc[j4 * 4 + 2]);
                acc[j4 * 4 + 3] = fmaf(xv[m], w.w, acc[j4 * 4 + 3]);
            }
        }
    }
    float* orow = o + (size_t)n * HH;
#pragma unroll
    for (int j4 = 0; j4 < 16; ++j4) {
        float4 v;
        v.x = acc[j4 * 4 + 0]; v.y = acc[j4 * 4 + 1];
        v.z = acc[j4 * 4 + 2]; v.w = acc[j4 * 4 + 3];
        *(float4*)(orow + j4 * 4) = v;
    }
}

// ---------------------------------------------------------------------------
// kP_fb: fallback (R6 kP) if ws_size is too small for xT.  Writes XA/XB/XC
// at xabc (same pointer kE/kF receive).
// ---------------------------------------------------------------------------
__global__ __launch_bounds__(256, 4) void kP_fb(const float* __restrict__ x,
                                                const float* __restrict__ ew1,
                                                const float* __restrict__ dw1,
                                                float* __restrict__ xabc) {
    int lane = threadIdx.x & 63;
    int wv = threadIdx.x >> 6;
    int r0 = blockIdx.x * 32 + wv * 8;
    if (r0 >= NN) return;
    const float* W0 = ew1;
    const float* W1 = ew1 + DD * HH;
    const float* W2 = dw1;
    const float* xw = x + (size_t)r0 * DD;
    float a0[8], a1[8], a2[8];
#pragma unroll
    for (int r = 0; r < 8; ++r) { a0[r] = 0.f; a1[r] = 0.f; a2[r] = 0.f; }
#pragma unroll 1
    for (int i4 = 0; i4 < DD / 4; ++i4) {
        float w00 = W0[(i4 * 4 + 0) * HH + lane];
        float w01 = W0[(i4 * 4 + 1) * HH + lane];
        float w02 = W0[(i4 * 4 + 2) * HH + lane];
        float w03 = W0[(i4 * 4 + 3) * HH + lane];
        float w10 = W1[(i4 * 4 + 0) * HH + lane];
        float w11 = W1[(i4 * 4 + 1) * HH + lane];
        float w12 = W1[(i4 * 4 + 2) * HH + lane];
        float w13 = W1[(i4 * 4 + 3) * HH + lane];
        float w20 = W2[(i4 * 4 + 0) * HH + lane];
        float w21 = W2[(i4 * 4 + 1) * HH + lane];
        float w22 = W2[(i4 * 4 + 2) * HH + lane];
        float w23 = W2[(i4 * 4 + 3) * HH + lane];
#pragma unroll
        for (int r = 0; r < 8; ++r) {
            float4 xv = *(const float4*)(xw + r * DD + i4 * 4);
            a0[r] = fmaf(xv.x, w00, a0[r]); a0[r] = fmaf(xv.y, w01, a0[r]);
            a0[r] = fmaf(xv.z, w02, a0[r]); a0[r] = fmaf(xv.w, w03, a0[r]);
            a1[r] = fmaf(xv.x, w10, a1[r]); a1[r] = fmaf(xv.y, w11, a1[r]);
            a1[r] = fmaf(xv.z, w12, a1[r]); a1[r] = fmaf(xv.w, w13, a1[r]);
            a2[r] = fmaf(xv.x, w20, a2[r]); a2[r] = fmaf(xv.y, w21, a2[r]);
            a2[r] = fmaf(xv.z, w22, a2[r]); a2[r] = fmaf(xv.w, w23, a2[r]);
        }
    }
    float* o0 = xabc + (size_t)r0 * HH + lane;
    float* o1 = xabc + (size_t)NN * HH + (size_t)r0 * HH + lane;
    float* o2 = xabc + 2 * (size_t)NN * HH + (size_t)r0 * HH + lane;
#pragma unroll
    for (int r = 0; r < 8; ++r) {
        o0[r * HH] = a0[r]; o1[r * HH] = a1[r]; o2[r * HH] = a2[r];
    }
}

// ---------------------------------------------------------------------------
// kE: thread-per-edge (unchanged — best measured 93 us).
// ---------------------------------------------------------------------------
__global__ __launch_bounds__(128, 4) void kE(const int* __restrict__ srcIdx,
                                             const float* __restrict__ dist,
                                             const float* __restrict__ xabc,
                                             const float* __restrict__ ew1,
                                             const float* __restrict__ eb1,
                                             const float* __restrict__ ew2,
                                             const float* __restrict__ eb2,
                                             const float* __restrict__ ew3,
                                             const float* __restrict__ eb3,
                                             float* __restrict__ energy_out) {
    int e = blockIdx.x * 128 + threadIdx.x;
    if (e >= NKE) return;
    int s = srcIdx[e];
    int d = e / KK;
    float dd = dist[e];
    const float* A = xabc + (size_t)d * HH;
    const float* B = xabc + (size_t)NN * HH + (size_t)s * HH;
    const float* w1l = ew1 + 2 * DD * HH;

    float acc[HH];
#pragma unroll
    for (int j = 0; j < HH; ++j) acc[j] = 0.f;

    float4 a4 = *(const float4*)A;
    float4 bp0 = *(const float4*)B;
    float4 bp1 = *(const float4*)(B + 4);
#pragma unroll 1
    for (int i4 = 0; i4 < HH / 4; ++i4) {
        float4 a = a4, b = bp0;
        int n1 = (i4 + 1 < 16) ? (i4 + 1) : 15;
        int n2 = (i4 + 2 < 16) ? (i4 + 2) : 15;
        a4 = *(const float4*)(A + n1 * 4);
        bp0 = bp1;
        bp1 = *(const float4*)(B + n2 * 4);
        float h[4];
        h[0] = fmaxf(a.x + b.x + dd * w1l[i4 * 4 + 0] + eb1[i4 * 4 + 0], 0.f);
        h[1] = fmaxf(a.y + b.y + dd * w1l[i4 * 4 + 1] + eb1[i4 * 4 + 1], 0.f);
        h[2] = fmaxf(a.z + b.z + dd * w1l[i4 * 4 + 2] + eb1[i4 * 4 + 2], 0.f);
        h[3] = fmaxf(a.w + b.w + dd * w1l[i4 * 4 + 3] + eb1[i4 * 4 + 3], 0.f);
#pragma unroll
        for (int k = 0; k < 4; ++k) {
            const float* wr = ew2 + (i4 * 4 + k) * HH;
#pragma unroll
            for (int j4 = 0; j4 < 16; ++j4) {
                float4 w = *(const float4*)(wr + j4 * 4);
                acc[j4 * 4 + 0] = fmaf(h[k], w.x, acc[j4 * 4 + 0]);
                acc[j4 * 4 + 1] = fmaf(h[k], w.y, acc[j4 * 4 + 1]);
                acc[j4 * 4 + 2] = fmaf(h[k], w.z, acc[j4 * 4 + 2]);
                acc[j4 * 4 + 3] = fmaf(h[k], w.w, acc[j4 * 4 + 3]);
            }
        }
    }
    float lg = eb3[0];
#pragma unroll
    for (int j = 0; j < HH; ++j)
        lg = fmaf(fmaxf(acc[j] + eb2[j], 0.f), ew3[j], lg);
    energy_out[e] = 1.f / (1.f + expf(-2.f * lg));
}

// ---------------------------------------------------------------------------
// kF: pure kE-clone node MLP (single pass, acc[64] AGPR, s_load weights read
// once) + register sort + hard gate + normalize.
// ---------------------------------------------------------------------------
__global__ __launch_bounds__(128, 4) void kF(const float* __restrict__ xabc,
                                             const float* __restrict__ dw1,
                                             const float* __restrict__ db1,
                                             const float* __restrict__ dw2,
                                             const float* __restrict__ db2,
                                             const float* __restrict__ dw3,
                                             const float* __restrict__ db3,
                                             float* __restrict__ out) {
    int n = blockIdx.x * 128 + threadIdx.x;
    if (n >= NN) return;
    const float* energy = out + 2 * (size_t)NKE;

    float ev[KK];
    float dh = 0.f;
#pragma unroll
    for (int j = 0; j < KK; ++j) {
        ev[j] = energy[(size_t)n * KK + j];
        dh += ev[j];
    }

    const float* XC = xabc + 2 * (size_t)NN * HH + (size_t)n * HH;
    const float* w1l = dw1 + DD * HH;

    float acc[HH];
#pragma unroll
    for (int j = 0; j < HH; ++j) acc[j] = 0.f;

    float4 c4 = *(const float4*)XC;
#pragma unroll 1
    for (int i4 = 0; i4 < HH / 4; ++i4) {
        float4 c = c4;
        int nx = (i4 + 1 < 16) ? (i4 + 1) : 15;
        c4 = *(const float4*)(XC + nx * 4);
        float cv[4] = {c.x, c.y, c.z, c.w};
#pragma unroll
        for (int m = 0; m < 4; ++m) {
            int k = i4 * 4 + m;
            float g = fmaxf(cv[m] + dh * w1l[k] + db1[k], 0.f);
            const float* wr = dw2 + k * HH;
#pragma unroll
            for (int j4 = 0; j4 < 16; ++j4) {
                float4 w = *(const float4*)(wr + j4 * 4);
                acc[j4 * 4 + 0] = fmaf(g, w.x, acc[j4 * 4 + 0]);
                acc[j4 * 4 + 1] = fmaf(g, w.y, acc[j4 * 4 + 1]);
                acc[j4 * 4 + 2] = fmaf(g, w.z, acc[j4 * 4 + 2]);
                acc[j4 * 4 + 3] = fmaf(g, w.w, acc[j4 * 4 + 3]);
            }
        }
    }
    float kraw = db3[0];
#pragma unroll
    for (int j = 0; j < HH; ++j)
        kraw = fmaf(fmaxf(acc[j] + db2[j], 0.f), dw3[j], kraw);

    float kcont = 2.f + 13.f / (1.f + expf(-kraw));
    out[3 * (size_t)NKE + n] = kcont;

    float se[16];
    int si[16];
#pragma unroll
    for (int j = 0; j < KK; ++j) { se[j] = ev[j]; si[j] = j; }
    se[15] = -1.f; si[15] = 15;

#pragma unroll
    for (int p = 1; p < 16; p <<= 1) {
#pragma unroll
        for (int k = p; k >= 1; k >>= 1) {
#pragma unroll
            for (int j = k & (p - 1); j + k < 16; j += 2 * k) {
#pragma unroll
                for (int i = 0; i < k; ++i) {
                    int a = i + j, b = i + j + k;
                    if (b < 16 && (a / (2 * p)) == (b / (2 * p))) {
                        bool sw = (se[b] > se[a]) ||
                                  (se[b] == se[a] && si[b] < si[a]);
                        float ea = sw ? se[b] : se[a];
                        float eb = sw ? se[a] : se[b];
                        int ia = sw ? si[b] : si[a];
                        int ib = sw ? si[a] : si[b];
                        se[a] = ea; se[b] = eb; si[a] = ia; si[b] = ib;
                    }
                }
            }
        }
    }

    float kint = rintf(kcont);
    kint = fminf(fmaxf(kint, 2.f), 15.f);

    float wsrt[KK];
    float denom = 0.f;
#pragma unroll
    for (int r = 0; r < KK; ++r) {
        float sel = ((float)(r + 1) <= kint) ? 1.f : 0.f;
        float wvv = se[r] * sel;
        wsrt[r] = wvv;
        denom += wvv;
    }
    denom = fmaxf(denom, 1e-12f);

#pragma unroll
    for (int r = 0; r < KK; ++r) {
        float sel = ((float)(r + 1) <= kint) ? 1.f : 0.f;
        int j0 = si[r];
        out[(size_t)NKE + (size_t)n * KK + j0] = sel;
        out[(size_t)n * KK + j0] = wsrt[r] / denom;
    }
}

extern "C" void kernel_launch(void* const* d_in, const int* in_sizes, int n_in,
                              void* d_out, int out_size, void* d_ws, size_t ws_size,
                              hipStream_t stream) {
    const float* x   = (const float*)d_in[0];
    const int*   ei  = (const int*)d_in[1];
    const float* ed  = (const float*)d_in[2];
    const float* ew1 = (const float*)d_in[3];
    const float* eb1 = (const float*)d_in[4];
    const float* ew2 = (const float*)d_in[5];
    const float* eb2 = (const float*)d_in[6];
    const float* ew3 = (const float*)d_in[7];
    const float* eb3 = (const float*)d_in[8];
    const float* dw1 = (const float*)d_in[9];
    const float* db1 = (const float*)d_in[10];
    const float* dw2 = (const float*)d_in[11];
    const float* db2 = (const float*)d_in[12];
    const float* dw3 = (const float*)d_in[13];
    const float* db3 = (const float*)d_in[14];
    float* out = (float*)d_out;
    float* ws  = (float*)d_ws;

    bool big = (ws_size >= WS_NEED);      // constant per deployment: capture-safe
    float* xabc = big ? (ws + TOFF) : ws;

    if (big) {
        hipLaunchKernelGGL(kT, dim3((NN + 63) / 64), dim3(256), 0, stream, x, ws);
        hipLaunchKernelGGL(kP2, dim3((NN + 127) / 128, 3), dim3(128), 0, stream,
                           ws, ew1, dw1, xabc);
    } else {
        hipLaunchKernelGGL(kP_fb, dim3((NN + 31) / 32), dim3(256), 0, stream,
                           x, ew1, dw1, xabc);
    }
    hipLaunchKernelGGL(kE, dim3((NKE + 127) / 128), dim3(128), 0, stream,
                       ei, ed, xabc, ew1, eb1, ew2, eb2, ew3, eb3,
                       out + 2 * (size_t)NKE);
    hipLaunchKernelGGL(kF, dim3((NN + 127) / 128), dim3(128), 0, stream,
                       xabc, dw1, db1, dw2, db2, dw3, db3, out);
}